// Round 1
// baseline (1274.448 us; speedup 1.0000x reference)
//
#include <hip/hip_runtime.h>
#include <math.h>

constexpr int kB  = 16;
constexpr int kS  = 256;
constexpr int kD  = 1024;
constexpr int kH  = 16;
constexpr int kDK = 64;
constexpr int kP  = 511;          // relpos rows used; p = z - s + 255
constexpr float kScale = 0.125f;  // 1/sqrt(64)

// ---------------- sinusoid table rows 257..767 of the reference table ----------------
// T[p][i], p in [0,511), corresponds to global row g = p + 257, pos = g - 512 = p - 255
__global__ void make_table_k(float* __restrict__ T) {
  int idx = blockIdx.x * 256 + threadIdx.x;
  if (idx >= kP * kD) return;
  int p = idx >> 10;
  int i = idx & 1023;
  double pos   = (double)(p - 255);
  double ex    = (double)(2 * (i / 2)) / 1024.0;
  double angle = pos / pow(10000.0, ex);
  T[idx] = (float)((i & 1) ? cos(angle) : sin(angle));
}

// ---------------- generic C = A @ W^T + bias ----------------
// A: M x K row-major, W: N x K row-major, C: M x N row-major.
// 64x64 block tile, BK=16, 256 threads, 4x4 per-thread microtile.
__global__ __launch_bounds__(256) void gemm_bias_k(
    const float* __restrict__ A, const float* __restrict__ W,
    const float* __restrict__ bias, float* __restrict__ C,
    int M, int N, int K) {
  __shared__ float As[16][68];  // As[k][m], stride 68 floats (272 B, 16B-aligned rows)
  __shared__ float Ws[16][68];  // Ws[k][n]

  const int bm = blockIdx.y * 64;
  const int bn = blockIdx.x * 64;
  const int t  = threadIdx.x;
  const int tx = t & 15;        // n microtile
  const int ty = t >> 4;        // m microtile

  float acc[4][4] = {{0.f}};

  const int lr = t >> 2;        // tile row 0..63
  const int lk = (t & 3) * 4;   // k offset 0,4,8,12

  for (int k0 = 0; k0 < K; k0 += 16) {
    float4 av;
    if (bm + lr < M)
      av = *reinterpret_cast<const float4*>(A + (size_t)(bm + lr) * K + k0 + lk);
    else
      av = make_float4(0.f, 0.f, 0.f, 0.f);
    As[lk + 0][lr] = av.x; As[lk + 1][lr] = av.y;
    As[lk + 2][lr] = av.z; As[lk + 3][lr] = av.w;

    float4 wv = *reinterpret_cast<const float4*>(W + (size_t)(bn + lr) * K + k0 + lk);
    Ws[lk + 0][lr] = wv.x; Ws[lk + 1][lr] = wv.y;
    Ws[lk + 2][lr] = wv.z; Ws[lk + 3][lr] = wv.w;

    __syncthreads();
#pragma unroll
    for (int kk = 0; kk < 16; ++kk) {
      float4 a = *reinterpret_cast<const float4*>(&As[kk][ty * 4]);
      float4 w = *reinterpret_cast<const float4*>(&Ws[kk][tx * 4]);
      acc[0][0] += a.x * w.x; acc[0][1] += a.x * w.y; acc[0][2] += a.x * w.z; acc[0][3] += a.x * w.w;
      acc[1][0] += a.y * w.x; acc[1][1] += a.y * w.y; acc[1][2] += a.y * w.z; acc[1][3] += a.y * w.w;
      acc[2][0] += a.z * w.x; acc[2][1] += a.z * w.y; acc[2][2] += a.z * w.z; acc[2][3] += a.z * w.w;
      acc[3][0] += a.w * w.x; acc[3][1] += a.w * w.y; acc[3][2] += a.w * w.z; acc[3][3] += a.w * w.w;
    }
    __syncthreads();
  }

#pragma unroll
  for (int i = 0; i < 4; ++i) {
    int row = bm + ty * 4 + i;
    if (row < M) {
#pragma unroll
      for (int j = 0; j < 4; ++j) {
        int col = bn + tx * 4 + j;
        C[(size_t)row * N + col] = acc[i][j] + bias[col];
      }
    }
  }
}

// ---------------- small bias-dot terms ----------------
// ut[(b*S+z)*H + h] = sum_d u_bias[h,d] * KR[(b*S+z)*D + h*64 + d]
// dt[h*511 + p]     = sum_d v_bias[h,d] * RPR[p*D + h*64 + d]
__global__ void bias_terms_k(const float* __restrict__ KR,
                             const float* __restrict__ RPR,
                             const float* __restrict__ ub,
                             const float* __restrict__ vb,
                             float* __restrict__ ut, float* __restrict__ dt) {
  int idx = blockIdx.x * 256 + threadIdx.x;
  const int NU = kB * kS * kH;  // 65536
  if (idx < NU) {
    int h = idx & 15, bz = idx >> 4;
    const float* kp = KR + (size_t)bz * kD + h * kDK;
    const float* up = ub + h * kDK;
    float a = 0.f;
#pragma unroll
    for (int d = 0; d < kDK; ++d) a += kp[d] * up[d];
    ut[idx] = a;
  } else if (idx < NU + kH * kP) {
    int j = idx - NU;
    int h = j / kP, p = j % kP;
    const float* rp = RPR + (size_t)p * kD + h * kDK;
    const float* vp = vb + h * kDK;
    float a = 0.f;
#pragma unroll
    for (int d = 0; d < kDK; ++d) a += rp[d] * vp[d];
    dt[j] = a;
  }
}

// ---------------- fused attention: scores + rel + softmax + attn@V ----------------
// One block per (b, h, s-tile of 32 rows). 256 threads.
__global__ __launch_bounds__(256) void attn_k(
    const float* __restrict__ Q, const float* __restrict__ Kb,
    const float* __restrict__ Vb, const float* __restrict__ RPK,
    const float* __restrict__ ut, const float* __restrict__ dt,
    float* __restrict__ O) {
  __shared__ float Qs[32][kDK + 4];        // 8.7 KB
  __shared__ float Sc[32][kS + 1];         // 32.9 KB
  __shared__ float Vs[kS][kDK + 4];        // 69.6 KB (only first zmax rows used)

  const int blk = blockIdx.x;
  const int st = blk & 7;
  const int h  = (blk >> 3) & 15;
  const int b  = blk >> 7;
  const int s0 = st * 32;
  const int zmax = s0 + 32;                // columns 0..zmax-1 can be unmasked
  const int t = threadIdx.x;

  // phase 0: stage Q tile and V rows [0, zmax)
  for (int l = t; l < 32 * 16; l += 256) {
    int r = l >> 4, c = (l & 15) * 4;
    *reinterpret_cast<float4*>(&Qs[r][c]) =
        *reinterpret_cast<const float4*>(Q + (size_t)(b * kS + s0 + r) * kD + h * kDK + c);
  }
  for (int l = t; l < zmax * 16; l += 256) {
    int r = l >> 4, c = (l & 15) * 4;
    *reinterpret_cast<float4*>(&Vs[r][c]) =
        *reinterpret_cast<const float4*>(Vb + (size_t)(b * kS + r) * kD + h * kDK + c);
  }
  __syncthreads();

  // phase 1a: thread = z column; Sc[s][z] = q_s . k_z + u_term[b,z,h]
  if (t < zmax) {
    const int z = t;
    float4 kreg[16];
    const float* kp = Kb + (size_t)(b * kS + z) * kD + h * kDK;
#pragma unroll
    for (int i = 0; i < 16; ++i) kreg[i] = *reinterpret_cast<const float4*>(kp + i * 4);
    float u = ut[(b * kS + z) * kH + h];
    for (int sl = 0; sl < 32; ++sl) {
      float a = 0.f;
#pragma unroll
      for (int i = 0; i < 16; ++i) {
        float4 q = *reinterpret_cast<const float4*>(&Qs[sl][i * 4]);
        a += kreg[i].x * q.x + kreg[i].y * q.y + kreg[i].z * q.z + kreg[i].w * q.w;
      }
      Sc[sl][z] = a + u;
    }
  }
  __syncthreads();

  // phase 1b: thread t -> relpos p = 255 - t; contributes to z = s - t per row
  if (t < zmax) {
    const int p = 255 - t;
    float4 rreg[16];
    const float* rp = RPK + (size_t)p * kD + h * kDK;
#pragma unroll
    for (int i = 0; i < 16; ++i) rreg[i] = *reinterpret_cast<const float4*>(rp + i * 4);
    float dv = dt[h * kP + p];
    for (int sl = 0; sl < 32; ++sl) {
      int z = s0 + sl - t;
      if (z >= 0) {
        float a = 0.f;
#pragma unroll
        for (int i = 0; i < 16; ++i) {
          float4 q = *reinterpret_cast<const float4*>(&Qs[sl][i * 4]);
          a += rreg[i].x * q.x + rreg[i].y * q.y + rreg[i].z * q.z + rreg[i].w * q.w;
        }
        Sc[sl][z] += a + dv;
      }
    }
  }
  __syncthreads();

  // phase 2: causal softmax per row; 8 threads per row
  {
    const int sl = t >> 3, l8 = t & 7;
    const int s = s0 + sl;
    float m = -1e30f;
    for (int z = l8; z <= s; z += 8) m = fmaxf(m, Sc[sl][z] * kScale);
    m = fmaxf(m, __shfl_xor(m, 1));
    m = fmaxf(m, __shfl_xor(m, 2));
    m = fmaxf(m, __shfl_xor(m, 4));
    float sum = 0.f;
    for (int z = l8; z <= s; z += 8) {
      float e = __expf(Sc[sl][z] * kScale - m);
      Sc[sl][z] = e;
      sum += e;
    }
    sum += __shfl_xor(sum, 1);
    sum += __shfl_xor(sum, 2);
    sum += __shfl_xor(sum, 4);
    float inv = 1.f / sum;
    for (int z = l8; z <= s; z += 8) Sc[sl][z] *= inv;
  }
  __syncthreads();

  // phase 3: O[s, d] = sum_z attn[s,z] * V[z,d]; thread = (row sl, 8-wide d chunk)
  {
    const int sl = t >> 3, dc = t & 7;
    const int s = s0 + sl;
    float acc[8] = {0.f};
    for (int z = 0; z <= s; ++z) {
      float a = Sc[sl][z];
      float4 v0 = *reinterpret_cast<const float4*>(&Vs[z][dc * 8]);
      float4 v1 = *reinterpret_cast<const float4*>(&Vs[z][dc * 8 + 4]);
      acc[0] += a * v0.x; acc[1] += a * v0.y; acc[2] += a * v0.z; acc[3] += a * v0.w;
      acc[4] += a * v1.x; acc[5] += a * v1.y; acc[6] += a * v1.z; acc[7] += a * v1.w;
    }
    float* op = O + (size_t)(b * kS + s) * kD + h * kDK + dc * 8;
    *reinterpret_cast<float4*>(op)     = make_float4(acc[0], acc[1], acc[2], acc[3]);
    *reinterpret_cast<float4*>(op + 4) = make_float4(acc[4], acc[5], acc[6], acc[7]);
  }
}

extern "C" void kernel_launch(void* const* d_in, const int* in_sizes, int n_in,
                              void* d_out, int out_size, void* d_ws, size_t ws_size,
                              hipStream_t stream) {
  const float* x  = (const float*)d_in[0];
  const float* Wq = (const float*)d_in[1];
  const float* bq = (const float*)d_in[2];
  const float* Wk = (const float*)d_in[3];
  const float* bk = (const float*)d_in[4];
  const float* Wv = (const float*)d_in[5];
  const float* bv = (const float*)d_in[6];
  const float* Wr = (const float*)d_in[7];
  const float* br = (const float*)d_in[8];
  const float* ub = (const float*)d_in[9];
  const float* vb = (const float*)d_in[10];
  const float* Wo = (const float*)d_in[11];
  const float* bo = (const float*)d_in[12];
  float* out = (float*)d_out;

  float* ws = (float*)d_ws;
  size_t off = 0;
  const size_t nBSD = (size_t)kB * kS * kD;  // 4194304
  float* Qb   = ws + off; off += nBSD;
  float* Kb   = ws + off; off += nBSD;
  float* Vbuf = ws + off; off += nBSD;
  float* KRb  = ws + off; off += nBSD;
  float* Tt   = ws + off; off += (size_t)kP * kD;
  float* RPKb = ws + off; off += (size_t)kP * kD;
  float* RPRb = ws + off; off += (size_t)kP * kD;
  float* ut   = ws + off; off += (size_t)kB * kS * kH;
  float* dt   = ws + off; off += (size_t)kH * kP;
  float* vw   = ws + off; off += nBSD;

  const int M  = kB * kS;  // 4096

  make_table_k<<<dim3((kP * kD + 255) / 256), dim3(256), 0, stream>>>(Tt);

  dim3 gbig(kD / 64, M / 64);
  gemm_bias_k<<<gbig, dim3(256), 0, stream>>>(x, Wq, bq, Qb,  M, kD, kD);
  gemm_bias_k<<<gbig, dim3(256), 0, stream>>>(x, Wk, bk, Kb,  M, kD, kD);
  gemm_bias_k<<<gbig, dim3(256), 0, stream>>>(x, Wv, bv, Vbuf, M, kD, kD);
  gemm_bias_k<<<gbig, dim3(256), 0, stream>>>(x, Wr, br, KRb, M, kD, kD);

  dim3 grel(kD / 64, (kP + 63) / 64);
  gemm_bias_k<<<grel, dim3(256), 0, stream>>>(Tt, Wk, bk, RPKb, kP, kD, kD);
  gemm_bias_k<<<grel, dim3(256), 0, stream>>>(Tt, Wr, br, RPRb, kP, kD, kD);

  bias_terms_k<<<dim3((kB * kS * kH + kH * kP + 255) / 256), dim3(256), 0, stream>>>(
      KRb, RPRb, ub, vb, ut, dt);

  attn_k<<<dim3(kB * kH * 8), dim3(256), 0, stream>>>(Qb, Kb, Vbuf, RPKb, ut, dt, vw);

  gemm_bias_k<<<gbig, dim3(256), 0, stream>>>(vw, Wo, bo, out, M, kD, kD);
}

// Round 2
// 293.606 us; speedup vs baseline: 4.3407x; 4.3407x over previous
//
#include <hip/hip_runtime.h>
#include <math.h>

constexpr int kB  = 16;
constexpr int kS  = 256;
constexpr int kD  = 1024;
constexpr int kH  = 16;
constexpr float kScale = 0.125f;  // 1/sqrt(64)

using bf16x8  = __attribute__((ext_vector_type(8))) short;
using floatx4 = __attribute__((ext_vector_type(4))) float;
typedef unsigned short u16;

__device__ __forceinline__ u16 f2bf(float x) {
  union { float f; unsigned u; } v; v.f = x;
  unsigned r = v.u + 0x7fffu + ((v.u >> 16) & 1u);
  return (u16)(r >> 16);
}
__device__ __forceinline__ float bf2f(u16 h) {
  union { unsigned u; float f; } v; v.u = ((unsigned)h) << 16;
  return v.f;
}

#define MFMA16(a, b, c) __builtin_amdgcn_mfma_f32_16x16x32_bf16((a), (b), (c), 0, 0, 0)
#define GLL16(gp, lp)                                                        \
  __builtin_amdgcn_global_load_lds(                                          \
      (const __attribute__((address_space(1))) unsigned int*)(gp),           \
      (__attribute__((address_space(3))) unsigned int*)(lp), 16, 0, 0)

// ---------------- sinusoid table rows: p in [0,256), pos = p-255, bf16 out --------
__global__ __launch_bounds__(256) void make_table_k(u16* __restrict__ T) {
  int idx = blockIdx.x * 256 + threadIdx.x;  // < 256*1024
  int p = idx >> 10;
  int i = idx & 1023;
  double pos   = (double)(p - 255);
  double ex    = (double)(2 * (i / 2)) / 1024.0;
  double angle = pos / pow(10000.0, ex);
  float v = (float)((i & 1) ? cos(angle) : sin(angle));
  T[idx] = f2bf(v);
}

// ---------------- cast/pack: xb, W4=[Wq;Wk;Wv;Wr], Wob, b4=[bq;bk;bv;br] ----------
__global__ __launch_bounds__(256) void pack_k(
    const float* __restrict__ x, const float* __restrict__ Wq,
    const float* __restrict__ Wk, const float* __restrict__ Wv,
    const float* __restrict__ Wr, const float* __restrict__ Wo,
    const float* __restrict__ bq, const float* __restrict__ bk,
    const float* __restrict__ bv, const float* __restrict__ br,
    u16* __restrict__ xb, u16* __restrict__ W4b, u16* __restrict__ Wob,
    float* __restrict__ b4) {
  size_t i = (size_t)blockIdx.x * 256 + threadIdx.x;
  const size_t NX = (size_t)4194304, NW = (size_t)1048576;
  if (i < NX) {
    xb[i] = f2bf(x[i]);
  } else if (i < NX + 4 * NW) {
    size_t j = i - NX;
    int sel = (int)(j >> 20);
    size_t o = j & (NW - 1);
    const float* src = sel == 0 ? Wq : sel == 1 ? Wk : sel == 2 ? Wv : Wr;
    W4b[j] = f2bf(src[o]);
  } else if (i < NX + 5 * NW) {
    size_t j = i - NX - 4 * NW;
    Wob[j] = f2bf(Wo[j]);
  } else if (i < NX + 5 * NW + 4096) {
    size_t j = i - NX - 5 * NW;
    int sel = (int)(j >> 10);
    size_t o = j & 1023;
    const float* src = sel == 0 ? bq : sel == 1 ? bk : sel == 2 ? bv : br;
    b4[j] = src[o];
  }
}

// ---------------- bf16 MFMA GEMM: C = A @ W^T + bias ----------------
// A: M x K bf16 row-major, W: N x K bf16 row-major. M,N multiples of 128, K of 64.
// 128x128 tile, BK=64, 256 threads (4 waves 2x2), XOR-swizzled LDS, GLL width 16.
template <int OUT_BF16>
__global__ __launch_bounds__(256) void gemm_k(
    const u16* __restrict__ A, const u16* __restrict__ W,
    const float* __restrict__ bias, void* __restrict__ Cv,
    int M, int N, int K) {
  __shared__ u16 Alds[128 * 64];
  __shared__ u16 Blds[128 * 64];
  const int bm = blockIdx.y * 128, bn = blockIdx.x * 128;
  const int t = threadIdx.x, w = t >> 6, l = t & 63;
  const int l15 = l & 15, quad = l >> 4;
  const int wm = w >> 1, wn = w & 1;
  const int lrow8 = l >> 3;   // 0..7
  const int kslot = l & 7;    // 0..7 (16B chunk within 128B row)

  floatx4 acc[4][4] = {};

  for (int k0 = 0; k0 < K; k0 += 64) {
#pragma unroll
    for (int sg = 0; sg < 4; ++sg) {
      int mrow = sg * 32 + w * 8 + lrow8;
      int gk = (kslot ^ (mrow & 7)) << 3;  // element offset of this 16B chunk
      const u16* gpa = A + (size_t)(bm + mrow) * K + k0 + gk;
      const u16* gpb = W + (size_t)(bn + mrow) * K + k0 + gk;
      u16* lpa = Alds + (sg * 32 + w * 8) * 64;  // wave-uniform base
      u16* lpb = Blds + (sg * 32 + w * 8) * 64;
      GLL16(gpa, lpa);
      GLL16(gpb, lpb);
    }
    __syncthreads();
#pragma unroll
    for (int c = 0; c < 2; ++c) {
      bf16x8 af[4], bf[4];
#pragma unroll
      for (int mi = 0; mi < 4; ++mi) {
        int am = wm * 64 + mi * 16 + l15;
        af[mi] = *(const bf16x8*)(Alds + am * 64 + (((c * 4 + quad) ^ (am & 7)) << 3));
      }
#pragma unroll
      for (int ni = 0; ni < 4; ++ni) {
        int an = wn * 64 + ni * 16 + l15;
        bf[ni] = *(const bf16x8*)(Blds + an * 64 + (((c * 4 + quad) ^ (an & 7)) << 3));
      }
#pragma unroll
      for (int mi = 0; mi < 4; ++mi)
#pragma unroll
        for (int ni = 0; ni < 4; ++ni)
          acc[mi][ni] = MFMA16(af[mi], bf[ni], acc[mi][ni]);
    }
    __syncthreads();
  }

#pragma unroll
  for (int ni = 0; ni < 4; ++ni) {
    int col = bn + wn * 64 + ni * 16 + l15;
    float bv = bias[col];
#pragma unroll
    for (int mi = 0; mi < 4; ++mi) {
      int mrow = bm + wm * 64 + mi * 16 + quad * 4;
#pragma unroll
      for (int r = 0; r < 4; ++r) {
        float v = acc[mi][ni][r] + bv;
        if (OUT_BF16)
          ((u16*)Cv)[(size_t)(mrow + r) * N + col] = f2bf(v);
        else
          ((float*)Cv)[(size_t)(mrow + r) * N + col] = v;
      }
    }
  }
}

// ---------------- V transpose: Vt[b][d][z] <- QKVR[(b*S+z)*4096 + 2048 + d] -------
__global__ __launch_bounds__(256) void transpose_v_k(const u16* __restrict__ Q4,
                                                     u16* __restrict__ Vt) {
  __shared__ u16 tile[32][36];
  int blk = blockIdx.x;
  int dt6 = blk & 31;         // d-tile
  int zt  = (blk >> 5) & 7;   // z-tile
  int b   = blk >> 8;
  int t = threadIdx.x;
  int r = t >> 3, cc = t & 7;
  const u16* gp = Q4 + (size_t)(b * 256 + zt * 32 + r) * 4096 + 2048 + dt6 * 32 + cc * 4;
  ushort4 vv = *(const ushort4*)gp;
  tile[r][cc * 4 + 0] = vv.x;
  tile[r][cc * 4 + 1] = vv.y;
  tile[r][cc * 4 + 2] = vv.z;
  tile[r][cc * 4 + 3] = vv.w;
  __syncthreads();
  ushort4 o;
  o.x = tile[cc * 4 + 0][r];
  o.y = tile[cc * 4 + 1][r];
  o.z = tile[cc * 4 + 2][r];
  o.w = tile[cc * 4 + 3][r];
  u16* op = Vt + (size_t)b * 262144 + (size_t)(dt6 * 32 + r) * 256 + zt * 32 + cc * 4;
  *(ushort4*)op = o;
}

// ---------------- small bias-dot terms (bf16 inputs) ----------------
// ut[(b*S+z)*H + h] = u_bias[h] . KR[b,z,h,:]   (KR = QKVR cols 3072..4095)
// dt[h*256 + p]     = v_bias[h] . RPR[p,h,:]
__global__ __launch_bounds__(256) void bias_terms_k(
    const u16* __restrict__ QKVR, const u16* __restrict__ RPR,
    const float* __restrict__ ub, const float* __restrict__ vb,
    float* __restrict__ ut, float* __restrict__ dt) {
  int idx = blockIdx.x * 256 + threadIdx.x;
  const int NU = kB * kS * kH;  // 65536
  if (idx < NU) {
    int h = idx & 15, bz = idx >> 4;
    const u16* kp = QKVR + (size_t)bz * 4096 + 3072 + h * 64;
    const float* up = ub + h * 64;
    float a = 0.f;
#pragma unroll
    for (int d = 0; d < 64; ++d) a += bf2f(kp[d]) * up[d];
    ut[idx] = a;
  } else if (idx < NU + kH * 256) {
    int j = idx - NU;
    int h = j >> 8, p = j & 255;
    const u16* rp = RPR + (size_t)p * 1024 + h * 64;
    const float* vp = vb + h * 64;
    float a = 0.f;
#pragma unroll
    for (int d = 0; d < 64; ++d) a += bf2f(rp[d]) * vp[d];
    dt[j] = a;
  }
}

// ---------------- fused MFMA attention ----------------
// Block = (b, h, 64-row s-tile). 4 waves; wave w owns rows [sB, sB+16), sB = s0+w*16.
// No __syncthreads: each wave touches only its own Sc rows.
__global__ __launch_bounds__(256) void attn_k(
    const u16* __restrict__ QKVR, const u16* __restrict__ RPK,
    const u16* __restrict__ Vt, const float* __restrict__ ut,
    const float* __restrict__ dt, u16* __restrict__ vw) {
  __shared__ float Sc[64][260];
  __shared__ float rinv[64];

  const int blk = blockIdx.x;
  const int st = blk & 3;
  const int h  = (blk >> 2) & 15;
  const int b  = blk >> 6;
  const int s0 = st * 64;

  const int t = threadIdx.x, w = t >> 6, l = t & 63;
  const int l15 = l & 15, quad = l >> 4;
  const int sB = s0 + w * 16;       // strip base row (global s)
  const int zT = sB / 16 + 1;       // z-tiles covering [0, sB+16)
  const int myrow = w * 16;         // Sc row base for this wave

  // Q A-fragments (held in regs for QK and QR phases)
  const u16* qp = QKVR + (size_t)(b * 256 + sB + l15) * 4096 + h * 64 + quad * 8;
  bf16x8 qa0 = *(const bf16x8*)qp;
  bf16x8 qa1 = *(const bf16x8*)(qp + 32);

  // ---- QK^T + u_term ----
  for (int zt = 0; zt < zT; ++zt) {
    int z0 = zt * 16;
    const u16* kp = QKVR + (size_t)(b * 256 + z0 + l15) * 4096 + 1024 + h * 64 + quad * 8;
    bf16x8 kb0 = *(const bf16x8*)kp;
    bf16x8 kb1 = *(const bf16x8*)(kp + 32);
    floatx4 acc = {};
    acc = MFMA16(qa0, kb0, acc);
    acc = MFMA16(qa1, kb1, acc);
    float u = ut[(b * 256 + z0 + l15) * 16 + h];
#pragma unroll
    for (int r = 0; r < 4; ++r)
      Sc[myrow + quad * 4 + r][z0 + l15] = acc[r] + u;
  }

  // ---- QR2[s,p] = q_s . RPK[p], scatter-add into Sc[s][p+s-255] (+ d_term) ----
  for (int pt = 0; pt < zT; ++pt) {
    int p0 = 240 - sB + pt * 16;
    const u16* rp = RPK + (size_t)(p0 + l15) * 1024 + h * 64 + quad * 8;
    bf16x8 rb0 = *(const bf16x8*)rp;
    bf16x8 rb1 = *(const bf16x8*)(rp + 32);
    floatx4 acc = {};
    acc = MFMA16(qa0, rb0, acc);
    acc = MFMA16(qa1, rb1, acc);
    float dv = dt[h * 256 + p0 + l15];
#pragma unroll
    for (int r = 0; r < 4; ++r) {
      int s = sB + quad * 4 + r;
      int z = p0 + l15 + s - 255;
      if (z >= 0) Sc[myrow + quad * 4 + r][z] += acc[r] + dv;
    }
  }

  // ---- causal softmax over the strip (unnormalized; 1/sum applied in epilogue) ----
  const int sr = l >> 2, c4 = l & 3;  // 16 rows x 4 lanes
  const int s = sB + sr;
  const int zPV = ((sB + 16 + 31) >> 5) << 5;  // PV k-range (multiple of 32)
  {
    float m = -1e30f;
    for (int z = c4; z <= s; z += 4) m = fmaxf(m, Sc[myrow + sr][z]);
    m = fmaxf(m, __shfl_xor(m, 1));
    m = fmaxf(m, __shfl_xor(m, 2));
    m *= kScale;
    float sum = 0.f;
    for (int z = c4; z < zPV; z += 4) {
      float e = 0.f;
      if (z <= s) {
        e = __expf(Sc[myrow + sr][z] * kScale - m);
        sum += e;
      }
      Sc[myrow + sr][z] = e;
    }
    sum += __shfl_xor(sum, 1);
    sum += __shfl_xor(sum, 2);
    if (c4 == 0) rinv[myrow + sr] = 1.f / sum;
  }

  // ---- PV: O[s,d] = sum_z P[s,z] * V[z,d] ----
  floatx4 oacc[4] = {};
  for (int kc = 0; kc < (zPV >> 5); ++kc) {
    const float* prow = &Sc[myrow + l15][kc * 32 + quad * 8];
    floatx4 p0 = *(const floatx4*)prow;
    floatx4 p1 = *(const floatx4*)(prow + 4);
    bf16x8 pa;
    pa[0] = (short)f2bf(p0[0]); pa[1] = (short)f2bf(p0[1]);
    pa[2] = (short)f2bf(p0[2]); pa[3] = (short)f2bf(p0[3]);
    pa[4] = (short)f2bf(p1[0]); pa[5] = (short)f2bf(p1[1]);
    pa[6] = (short)f2bf(p1[2]); pa[7] = (short)f2bf(p1[3]);
#pragma unroll
    for (int nt = 0; nt < 4; ++nt) {
      const u16* vp = Vt + (size_t)b * 262144 +
                      (size_t)(h * 64 + nt * 16 + l15) * 256 + kc * 32 + quad * 8;
      bf16x8 vbf = *(const bf16x8*)vp;
      oacc[nt] = MFMA16(pa, vbf, oacc[nt]);
    }
  }

  // ---- epilogue: normalize, cast bf16, store ----
  floatx4 iv = *(const floatx4*)&rinv[myrow + quad * 4];
#pragma unroll
  for (int nt = 0; nt < 4; ++nt) {
#pragma unroll
    for (int r = 0; r < 4; ++r) {
      int srow = sB + quad * 4 + r;
      float val = oacc[nt][r] * iv[r];
      vw[(size_t)(b * 256 + srow) * 1024 + h * 64 + nt * 16 + l15] = f2bf(val);
    }
  }
}

extern "C" void kernel_launch(void* const* d_in, const int* in_sizes, int n_in,
                              void* d_out, int out_size, void* d_ws, size_t ws_size,
                              hipStream_t stream) {
  const float* x  = (const float*)d_in[0];
  const float* Wq = (const float*)d_in[1];
  const float* bq = (const float*)d_in[2];
  const float* Wk = (const float*)d_in[3];
  const float* bk = (const float*)d_in[4];
  const float* Wv = (const float*)d_in[5];
  const float* bv = (const float*)d_in[6];
  const float* Wr = (const float*)d_in[7];
  const float* br = (const float*)d_in[8];
  const float* ub = (const float*)d_in[9];
  const float* vb = (const float*)d_in[10];
  const float* Wo = (const float*)d_in[11];
  const float* bo = (const float*)d_in[12];
  float* out = (float*)d_out;

  char* base = (char*)d_ws;
  size_t off = 0;
  auto alloc = [&](size_t bytes) {
    void* p = base + off;
    off += (bytes + 255) & ~(size_t)255;
    return p;
  };

  u16*   Tt    = (u16*)alloc((size_t)256 * 1024 * 2);        // table bf16
  u16*   xb    = (u16*)alloc((size_t)4096 * 1024 * 2);       // x bf16
  u16*   W4b   = (u16*)alloc((size_t)4096 * 1024 * 2);       // [Wq;Wk;Wv;Wr] bf16
  u16*   Wob   = (u16*)alloc((size_t)1024 * 1024 * 2);       // Wo bf16
  float* b4    = (float*)alloc((size_t)4096 * 4);            // [bq;bk;bv;br]
  u16*   QKVRb = (u16*)alloc((size_t)4096 * 4096 * 2);       // fused projections bf16
  u16*   RPKb  = (u16*)alloc((size_t)256 * 1024 * 2);
  u16*   RPRb  = (u16*)alloc((size_t)256 * 1024 * 2);
  u16*   Vt    = (u16*)alloc((size_t)16 * 1024 * 256 * 2);   // V transposed
  float* ut    = (float*)alloc((size_t)65536 * 4);
  float* dtb   = (float*)alloc((size_t)16 * 256 * 4);
  u16*   vwb   = (u16*)alloc((size_t)4096 * 1024 * 2);       // attention out bf16

  make_table_k<<<dim3(1024), dim3(256), 0, stream>>>(Tt);
  pack_k<<<dim3(36880), dim3(256), 0, stream>>>(x, Wq, Wk, Wv, Wr, Wo, bq, bk, bv, br,
                                                xb, W4b, Wob, b4);

  // fused Q|K|V|KR projection: 4096 x 4096 x 1024
  gemm_k<1><<<dim3(32, 32), dim3(256), 0, stream>>>(xb, W4b, b4, QKVRb, 4096, 4096, 1024);
  // rel-pos projections (only p<256 survives the causal mask): 256 x 1024 x 1024
  gemm_k<1><<<dim3(8, 2), dim3(256), 0, stream>>>(Tt, W4b + (size_t)1024 * 1024,
                                                  b4 + 1024, RPKb, 256, 1024, 1024);
  gemm_k<1><<<dim3(8, 2), dim3(256), 0, stream>>>(Tt, W4b + (size_t)3072 * 1024,
                                                  b4 + 3072, RPRb, 256, 1024, 1024);

  transpose_v_k<<<dim3(4096), dim3(256), 0, stream>>>(QKVRb, Vt);
  bias_terms_k<<<dim3(272), dim3(256), 0, stream>>>(QKVRb, RPRb, ub, vb, ut, dtb);

  attn_k<<<dim3(1024), dim3(256), 0, stream>>>(QKVRb, RPKb, Vt, ut, dtb, vwb);

  // output projection: 4096 x 1024 x 1024, fp32 out
  gemm_k<0><<<dim3(8, 32), dim3(256), 0, stream>>>(vwb, Wob, bo, out, 4096, 1024, 1024);
}